// Round 1
// baseline (553.502 us; speedup 1.0000x reference)
//
#include <hip/hip_runtime.h>
#include <math.h>

// Problem constants
#define C_TOTAL 3072
#define C4 2048      // channels from l4 (upsampled)
#define C3 1024      // channels from l3
#define HW  784      // 28*28
#define W_  28
#define L_TOT 9      // landmarks + 1
#define NB  16       // batch
#define NK  2000     // classes
#define NGROUPS 16
#define CCHUNK (C_TOTAL / NGROUPS)   // 192

// Bilinear upsample 14->28, align_corners=False / jax.image.resize semantics:
// src = 0.5*o - 0.25; even o=2j: taps (j-1, j) w (0.25, 0.75); odd o=2j+1: taps (j, j+1) w (0.75, 0.25); clamp.
__device__ __forceinline__ void up_taps(int o, int& i0, int& i1, float& w0, float& w1) {
    int j = o >> 1;
    if (o & 1) { i0 = j;              i1 = (j + 1 < 14) ? j + 1 : 13; w0 = 0.75f; w1 = 0.25f; }
    else       { i0 = (j - 1 > 0) ? j - 1 : 0; i1 = j;               w0 = 0.25f; w1 = 0.75f; }
}

// ---------------- Kernel B: landmark maps (softmax over 9 "distance" logits) ---------------
// logits_l = -(bsq - 2 ab_l + asq_l); bsq constant over l -> softmax(2*ab_l - asq_l).
// Block: 1024 threads = 64 pixels x 16 channel-groups. Grid: (ceil(784/64)=13, 16 batches).
__global__ __launch_bounds__(1024) void landmark_maps_kernel(
    const float* __restrict__ l3, const float* __restrict__ l4,
    const float* __restrict__ Wl, float* __restrict__ maps_out)
{
    __shared__ float red[NGROUPS][64][L_TOT];   // 36864 B
    __shared__ float logits[64][L_TOT];
    __shared__ float asq[L_TOT];

    const int tid = threadIdx.x;
    const int px  = tid & 63;
    const int grp = tid >> 6;
    const int b   = blockIdx.y;
    const int pg  = blockIdx.x * 64 + px;
    const bool valid = (pg < HW);

    // asq[l] = sum_c Wl[l][c]^2 ; waves 0..8 (one wave per l), coalesced over c
    if (grp < L_TOT) {
        float s = 0.f;
        const float* wrow = Wl + grp * C_TOTAL;
        for (int c = px; c < C_TOTAL; c += 64) { float w = wrow[c]; s = fmaf(w, w, s); }
        #pragma unroll
        for (int off = 32; off; off >>= 1) s += __shfl_down(s, off, 64);
        if (px == 0) asq[grp] = s;
    }

    const int ppg = valid ? pg : 0;
    const int y = ppg / W_, x = ppg % W_;
    int y0, y1, x0, x1; float wy0, wy1, wx0, wx1;
    up_taps(y, y0, y1, wy0, wy1);
    up_taps(x, x0, x1, wx0, wx1);
    const int o00 = y0 * 14 + x0, o01 = y0 * 14 + x1;
    const int o10 = y1 * 14 + x0, o11 = y1 * 14 + x1;

    const float* l4b = l4 + (size_t)b * C4 * 196;
    const float* l3b = l3 + (size_t)b * C3 * HW;

    float ab[L_TOT];
    #pragma unroll
    for (int l = 0; l < L_TOT; ++l) ab[l] = 0.f;

    const int c_begin = grp * CCHUNK, c_end = c_begin + CCHUNK;
    for (int c = c_begin; c < c_end; ++c) {
        float xv;
        if (c < C4) {   // uniform branch
            const float* pc = l4b + c * 196;  // uniform base + lane-varying offsets
            float v00 = pc[o00], v01 = pc[o01], v10 = pc[o10], v11 = pc[o11];
            float t0 = fmaf(v01, wx1, v00 * wx0);
            float t1 = fmaf(v11, wx1, v10 * wx0);
            xv = fmaf(t1, wy1, t0 * wy0);
        } else {
            xv = l3b[(c - C4) * HW + ppg];    // coalesced (lanes = consecutive pixels)
        }
        const float* wc = Wl + c;             // uniform -> scalar loads
        #pragma unroll
        for (int l = 0; l < L_TOT; ++l) ab[l] = fmaf(wc[l * C_TOTAL], xv, ab[l]);
    }
    #pragma unroll
    for (int l = 0; l < L_TOT; ++l) red[grp][px][l] = ab[l];
    __syncthreads();

    // reduce across 16 groups: 576 threads: (px, l)
    if (tid < 64 * L_TOT) {
        const int l = tid >> 6, p = tid & 63;
        float s = 0.f;
        #pragma unroll
        for (int g = 0; g < NGROUPS; ++g) s += red[g][p][l];
        logits[p][l] = 2.f * s - asq[l];
    }
    __syncthreads();

    if (tid < 64 && valid) {
        float lg[L_TOT];
        #pragma unroll
        for (int l = 0; l < L_TOT; ++l) lg[l] = logits[px][l];
        float m = lg[0];
        #pragma unroll
        for (int l = 1; l < L_TOT; ++l) m = fmaxf(m, lg[l]);
        float sum = 0.f;
        #pragma unroll
        for (int l = 0; l < L_TOT; ++l) { lg[l] = __expf(lg[l] - m); sum += lg[l]; }
        const float inv = 1.f / sum;
        float* mp = maps_out + (size_t)b * L_TOT * HW + pg;
        #pragma unroll
        for (int l = 0; l < L_TOT; ++l) mp[l * HW] = lg[l] * inv;  // coalesced per l
    }
}

// ---------------- Kernel C: weighted spatial pooling -> all_features (+ g for classifier) ----
// af[b][c][l] = (1/784) sum_p maps[b][l][p] * x[b][c][p]
// g[b][c]     = (1/8)   sum_{l<8} mod[c][l] * af[b][c][l]
// Thread per channel; pixels split into 4 chunks of 196 (7 rows); partial sums via atomicAdd.
__global__ __launch_bounds__(256) void pool_kernel(
    const float* __restrict__ l3, const float* __restrict__ l4,
    const float* __restrict__ maps, const float* __restrict__ modulation,
    float* __restrict__ af_out, float* __restrict__ g_out)
{
    const int c  = blockIdx.x * 256 + threadIdx.x;  // < 3072 exactly
    const int b  = blockIdx.y;
    const int pz = blockIdx.z;                      // pixel chunk 0..3

    float acc[L_TOT];
    #pragma unroll
    for (int l = 0; l < L_TOT; ++l) acc[l] = 0.f;

    const float* mb = maps + (size_t)b * L_TOT * HW;

    if (c < C4) {
        const float* pc = l4 + ((size_t)b * C4 + c) * 196;
        for (int y = pz * 7; y < pz * 7 + 7; ++y) {
            int y0, y1; float wy0, wy1;
            up_taps(y, y0, y1, wy0, wy1);
            const float* r0 = pc + y0 * 14;
            const float* r1 = pc + y1 * 14;
            for (int xq = 0; xq < W_; ++xq) {
                int x0, x1; float wx0, wx1;
                up_taps(xq, x0, x1, wx0, wx1);
                float t0 = fmaf(r0[x1], wx1, r0[x0] * wx0);
                float t1 = fmaf(r1[x1], wx1, r1[x0] * wx0);
                float xv = fmaf(t1, wy1, t0 * wy0);
                const int p = y * W_ + xq;
                #pragma unroll
                for (int l = 0; l < L_TOT; ++l) acc[l] = fmaf(mb[l * HW + p], xv, acc[l]);
            }
        }
    } else {
        const float* pc = l3 + ((size_t)b * C3 + (c - C4)) * HW;
        const int p0 = pz * 196;
        for (int p = p0; p < p0 + 196; ++p) {
            float xv = pc[p];
            #pragma unroll
            for (int l = 0; l < L_TOT; ++l) acc[l] = fmaf(mb[l * HW + p], xv, acc[l]);
        }
    }

    const float inv_hw = 1.f / 784.f;
    float* afp = af_out + ((size_t)b * C_TOTAL + c) * L_TOT;
    float gp = 0.f;
    #pragma unroll
    for (int l = 0; l < L_TOT; ++l) {
        float v = acc[l] * inv_hw;
        atomicAdd(&afp[l], v);
        if (l < 8) gp = fmaf(modulation[c * L_TOT + l], v, gp);
    }
    atomicAdd(&g_out[(size_t)b * C_TOTAL + c], gp * 0.125f);
}

// ---------------- Kernel D: class_scores = g (16x3072) @ W_class^T (3072x2000) ---------------
// Wave per k (500 blocks x 4 waves = 2000), float4 loads, 16 batch accumulators, shuffle reduce.
__global__ __launch_bounds__(256) void class_kernel(
    const float* __restrict__ Wc, const float* __restrict__ g,
    float* __restrict__ out)
{
    const int wv   = threadIdx.x >> 6;
    const int lane = threadIdx.x & 63;
    const int k    = blockIdx.x * 4 + wv;

    const float4* w4p = (const float4*)(Wc + (size_t)k * C_TOTAL);
    float acc[NB];
    #pragma unroll
    for (int b = 0; b < NB; ++b) acc[b] = 0.f;

    for (int i = 0; i < C_TOTAL / 256; ++i) {   // 12 iters, 256 floats (64 float4) per iter
        const int c4i = i * 64 + lane;
        float4 w4 = w4p[c4i];
        #pragma unroll
        for (int b = 0; b < NB; ++b) {
            float4 g4 = ((const float4*)(g + (size_t)b * C_TOTAL))[c4i];
            acc[b] = fmaf(w4.x, g4.x, acc[b]);
            acc[b] = fmaf(w4.y, g4.y, acc[b]);
            acc[b] = fmaf(w4.z, g4.z, acc[b]);
            acc[b] = fmaf(w4.w, g4.w, acc[b]);
        }
    }
    #pragma unroll
    for (int b = 0; b < NB; ++b) {
        #pragma unroll
        for (int off = 32; off; off >>= 1) acc[b] += __shfl_down(acc[b], off, 64);
    }
    if (lane == 0) {
        #pragma unroll
        for (int b = 0; b < NB; ++b) out[(size_t)b * NK + k] = acc[b];
    }
}

extern "C" void kernel_launch(void* const* d_in, const int* in_sizes, int n_in,
                              void* d_out, int out_size, void* d_ws, size_t ws_size,
                              hipStream_t stream) {
    const float* l3  = (const float*)d_in[0];  // (16,1024,28,28)
    const float* l4  = (const float*)d_in[1];  // (16,2048,14,14)
    const float* Wl  = (const float*)d_in[2];  // (9,3072)
    const float* Wc  = (const float*)d_in[3];  // (2000,3072)
    const float* mod = (const float*)d_in[4];  // (1,3072,9)

    float* out  = (float*)d_out;
    float* cls  = out;             // 16*2000           = 32000
    float* maps = out + 32000;     // 16*9*784          = 112896
    float* af   = out + 144896;    // 16*3072*9         = 442368
    float* g    = (float*)d_ws;    // 16*3072 floats    = 196608 B

    hipMemsetAsync(af, 0, (size_t)NB * C_TOTAL * L_TOT * sizeof(float), stream);
    hipMemsetAsync(g,  0, (size_t)NB * C_TOTAL * sizeof(float), stream);

    landmark_maps_kernel<<<dim3((HW + 63) / 64, NB), 1024, 0, stream>>>(l3, l4, Wl, maps);
    pool_kernel<<<dim3(C_TOTAL / 256, NB, 4), 256, 0, stream>>>(l3, l4, maps, mod, af, g);
    class_kernel<<<NK / 4, 256, 0, stream>>>(Wc, g, cls);
}

// Round 2
// 246.318 us; speedup vs baseline: 2.2471x; 2.2471x over previous
//
#include <hip/hip_runtime.h>
#include <math.h>

// Problem constants
#define C_TOTAL 3072
#define C4 2048      // channels from l4 (upsampled half of concat: channels [0,2048))
#define C3 1024      // channels from l3 (channels [2048,3072))
#define HW  784      // 28*28
#define W_  28
#define HW4 196      // 14*14
#define W4  14
#define L_TOT 9      // landmarks + 1
#define NB  16       // batch
#define NK  2000     // classes

// Bilinear upsample 14->28, align_corners=False (jax.image.resize semantics):
// src = 0.5*o - 0.25; even o=2j: taps (j-1, j) w (0.25, 0.75); odd o=2j+1: taps (j, j+1) w (0.75, 0.25); clamp.
__device__ __forceinline__ void up_taps(int o, int& i0, int& i1, float& w0, float& w1) {
    int j = o >> 1;
    if (o & 1) { i0 = j;                       i1 = (j + 1 < W4) ? j + 1 : W4 - 1; w0 = 0.75f; w1 = 0.25f; }
    else       { i0 = (j - 1 > 0) ? j - 1 : 0; i1 = j;                             w0 = 0.25f; w1 = 0.75f; }
}

// weight that source index s contributes to output index o (adjoint of the upsample)
__device__ __forceinline__ float wdown(int o, int s) {
    int i0, i1; float w0, w1;
    up_taps(o, i0, i1, w0, w1);
    return (i0 == s ? w0 : 0.f) + (i1 == s ? w1 : 0.f);
}

// ------------- K1a: ab4 partials — ab4[b,l,q] = sum_{c<2048} Wl[l,c]*l4[b,c,q] on the 14x14 grid ---
// Grid: (16 channel-chunks of 128, 16 batches). Block 256; thread = source pixel q (<196).
__global__ __launch_bounds__(256) void ab4_kernel(
    const float* __restrict__ l4, const float* __restrict__ Wl,
    float* __restrict__ ab4p)
{
    const int q  = threadIdx.x;
    const int cb = blockIdx.x;   // 0..15
    const int b  = blockIdx.y;
    if (q >= HW4) return;

    const float* l4b = l4 + (size_t)b * C4 * HW4;
    float acc[L_TOT];
    #pragma unroll
    for (int l = 0; l < L_TOT; ++l) acc[l] = 0.f;

    const int c0 = cb * 128;
    for (int i = 0; i < 128; ++i) {
        const int c = c0 + i;                       // wave-uniform -> scalar weight loads
        float xv = l4b[(size_t)c * HW4 + q];        // coalesced over q
        const float* wc = Wl + c;
        #pragma unroll
        for (int l = 0; l < L_TOT; ++l) acc[l] = fmaf(wc[l * C_TOTAL], xv, acc[l]);
    }
    float* outp = ab4p + (size_t)(cb * NB + b) * (L_TOT * HW4) + q;
    #pragma unroll
    for (int l = 0; l < L_TOT; ++l) outp[l * HW4] = acc[l];
}

// ------------- K1b: l3 contribution + upsample(ab4) + softmax -> maps -------------------------------
// Block 1024 = 64 px * 16 channel-groups (64 ch each). Grid: (13 pixel blocks, 16 batches).
__global__ __launch_bounds__(1024) void maps_kernel(
    const float* __restrict__ l3, const float* __restrict__ Wl,
    const float* __restrict__ ab4p, float* __restrict__ maps_out)
{
    __shared__ float red[16][64][L_TOT];   // 36864 B
    __shared__ float ab4s[L_TOT * HW4];    // 7056 B
    __shared__ float logits[64][L_TOT];
    __shared__ float asq[L_TOT];

    const int tid = threadIdx.x;
    const int px  = tid & 63;
    const int grp = tid >> 6;
    const int b   = blockIdx.y;
    const int pg  = blockIdx.x * 64 + px;
    const bool valid = (pg < HW);

    // sum the 16 ab4 partials into LDS
    for (int v = tid; v < L_TOT * HW4; v += 1024) {
        float ss = 0.f;
        #pragma unroll
        for (int j = 0; j < 16; ++j) ss += ab4p[(size_t)(j * NB + b) * (L_TOT * HW4) + v];
        ab4s[v] = ss;
    }
    // asq[l] = sum_c Wl[l][c]^2 (waves 0..8)
    if (grp < L_TOT) {
        float s = 0.f;
        const float* wrow = Wl + grp * C_TOTAL;
        for (int c = px; c < C_TOTAL; c += 64) { float w = wrow[c]; s = fmaf(w, w, s); }
        #pragma unroll
        for (int off = 32; off; off >>= 1) s += __shfl_down(s, off, 64);
        if (px == 0) asq[grp] = s;
    }

    // l3 contribution: group handles 64 channels, lanes = pixels (coalesced)
    const int ppg = valid ? pg : 0;
    const float* l3b = l3 + (size_t)b * C3 * HW;
    float ab[L_TOT];
    #pragma unroll
    for (int l = 0; l < L_TOT; ++l) ab[l] = 0.f;
    const int c0 = grp * 64;
    for (int i = 0; i < 64; ++i) {
        const int c = c0 + i;
        float xv = l3b[(size_t)c * HW + ppg];
        const float* wc = Wl + C4 + c;
        #pragma unroll
        for (int l = 0; l < L_TOT; ++l) ab[l] = fmaf(wc[l * C_TOTAL], xv, ab[l]);
    }
    #pragma unroll
    for (int l = 0; l < L_TOT; ++l) red[grp][px][l] = ab[l];
    __syncthreads();

    // combine 16 groups + upsampled ab4 -> logits
    if (tid < 64 * L_TOT) {
        const int l = tid >> 6, p = tid & 63;
        float ssum = 0.f;
        #pragma unroll
        for (int g = 0; g < 16; ++g) ssum += red[g][p][l];
        const int pgl = blockIdx.x * 64 + p;
        float up = 0.f;
        if (pgl < HW) {
            const int y = pgl / W_, x = pgl % W_;
            int y0, y1, x0, x1; float wy0, wy1, wx0, wx1;
            up_taps(y, y0, y1, wy0, wy1);
            up_taps(x, x0, x1, wx0, wx1);
            const float* a = ab4s + l * HW4;
            float t0 = fmaf(a[y0 * W4 + x1], wx1, a[y0 * W4 + x0] * wx0);
            float t1 = fmaf(a[y1 * W4 + x1], wx1, a[y1 * W4 + x0] * wx0);
            up = fmaf(t1, wy1, t0 * wy0);
        }
        logits[p][l] = 2.f * (ssum + up) - asq[l];
    }
    __syncthreads();

    if (tid < 64 && valid) {
        float lg[L_TOT];
        #pragma unroll
        for (int l = 0; l < L_TOT; ++l) lg[l] = logits[px][l];
        float m = lg[0];
        #pragma unroll
        for (int l = 1; l < L_TOT; ++l) m = fmaxf(m, lg[l]);
        float sum = 0.f;
        #pragma unroll
        for (int l = 0; l < L_TOT; ++l) { lg[l] = __expf(lg[l] - m); sum += lg[l]; }
        const float inv = 1.f / sum;
        float* mp = maps_out + (size_t)b * L_TOT * HW + pg;
        #pragma unroll
        for (int l = 0; l < L_TOT; ++l) mp[l * HW] = lg[l] * inv;
    }
}

// ------------- K2: pooling -> all_features + g ------------------------------------------------------
// Block 256 = 4 waves x (4 ch-subgroups x 16 px-lanes); each lane owns 4 consecutive channels.
// l4 blocks (cblk<32): downsample-adjoint maps into LDS, read l4 directly (no upsample).
// l3 blocks: stage maps[9][784] into LDS. Block owns full pixel range -> no atomics.
__global__ __launch_bounds__(256) void pool_kernel(
    const float* __restrict__ l3, const float* __restrict__ l4,
    const float* __restrict__ maps, const float* __restrict__ modulation,
    float* __restrict__ af_out, float* __restrict__ g_out)
{
    __shared__ float msh[L_TOT * HW];   // 28224 B; l4 blocks use first 9*196

    const int tid  = threadIdx.x;
    const int b    = blockIdx.y;
    const int cblk = blockIdx.x;        // 0..47
    const bool isl4 = (cblk < 32);
    const float* mb = maps + (size_t)b * L_TOT * HW;

    if (isl4) {
        // maps_down[l][sy][sx] = sum_{oy,ox} wdown(oy,sy)*wdown(ox,sx)*maps[l][oy][ox]
        for (int v = tid; v < L_TOT * HW4; v += 256) {
            const int l = v / HW4, q = v % HW4;
            const int sy = q / W4, sx = q % W4;
            float s = 0.f;
            int oy0 = 2 * sy - 1; if (oy0 < 0) oy0 = 0;
            int oy1 = 2 * sy + 2; if (oy1 > 27) oy1 = 27;
            int ox0 = 2 * sx - 1; if (ox0 < 0) ox0 = 0;
            int ox1 = 2 * sx + 2; if (ox1 > 27) ox1 = 27;
            for (int oy = oy0; oy <= oy1; ++oy) {
                const float wy = wdown(oy, sy);
                const float* row = mb + l * HW + oy * W_;
                for (int ox = ox0; ox <= ox1; ++ox)
                    s = fmaf(wy * wdown(ox, sx), row[ox], s);
            }
            msh[v] = s;
        }
    } else {
        for (int v = tid; v < (L_TOT * HW) / 4; v += 256)
            ((float4*)msh)[v] = ((const float4*)mb)[v];
    }
    __syncthreads();

    const int   PMAX  = isl4 ? HW4 : HW;
    const float* xbase = isl4 ? (l4 + (size_t)b * C4 * HW4)
                              : (l3 + (size_t)b * C3 * HW);
    const int cloc0 = (isl4 ? cblk : (cblk - 32)) * 64;
    const int w = tid >> 6, s = (tid >> 4) & 3, t = tid & 15;
    const int cl = cloc0 + w * 16 + s * 4;      // local channel base of this lane's 4 channels

    float acc[4][L_TOT];
    #pragma unroll
    for (int j = 0; j < 4; ++j)
        #pragma unroll
        for (int l = 0; l < L_TOT; ++l) acc[j][l] = 0.f;

    const int kmax = isl4 ? 4 : 13;
    for (int k = 0; k < kmax; ++k) {
        const int p = (t << 2) + (k << 6);
        if (p < PMAX) {
            float4 m4[L_TOT];
            #pragma unroll
            for (int l = 0; l < L_TOT; ++l) m4[l] = *(const float4*)&msh[l * PMAX + p];
            #pragma unroll
            for (int j = 0; j < 4; ++j) {
                float4 x4 = *(const float4*)&xbase[(size_t)(cl + j) * PMAX + p];
                #pragma unroll
                for (int l = 0; l < L_TOT; ++l)
                    acc[j][l] = fmaf(x4.x, m4[l].x, fmaf(x4.y, m4[l].y,
                                fmaf(x4.z, m4[l].z, fmaf(x4.w, m4[l].w, acc[j][l]))));
            }
        }
    }

    // reduce across the 16 pixel-lanes of each subgroup
    #pragma unroll
    for (int j = 0; j < 4; ++j)
        #pragma unroll
        for (int l = 0; l < L_TOT; ++l) {
            float v = acc[j][l];
            v += __shfl_xor(v, 1, 16);
            v += __shfl_xor(v, 2, 16);
            v += __shfl_xor(v, 4, 16);
            v += __shfl_xor(v, 8, 16);
            acc[j][l] = v;
        }

    if (t == 0) {
        const float inv_hw = 1.f / 784.f;
        #pragma unroll
        for (int j = 0; j < 4; ++j) {
            const int cg = (isl4 ? 0 : C4) + cl + j;    // global concat channel
            float* afp = af_out + ((size_t)b * C_TOTAL + cg) * L_TOT;
            float gp = 0.f;
            #pragma unroll
            for (int l = 0; l < L_TOT; ++l) {
                float v = acc[j][l] * inv_hw;
                afp[l] = v;
                if (l < 8) gp = fmaf(modulation[cg * L_TOT + l], v, gp);
            }
            g_out[(size_t)b * C_TOTAL + cg] = gp * 0.125f;
        }
    }
}

// ------------- K3: class_scores = g (16x3072) @ W_class^T (3072x2000) -------------------------------
__global__ __launch_bounds__(256) void class_kernel(
    const float* __restrict__ Wc, const float* __restrict__ g,
    float* __restrict__ out)
{
    const int wv   = threadIdx.x >> 6;
    const int lane = threadIdx.x & 63;
    const int k    = blockIdx.x * 4 + wv;

    const float4* w4p = (const float4*)(Wc + (size_t)k * C_TOTAL);
    float acc[NB];
    #pragma unroll
    for (int b = 0; b < NB; ++b) acc[b] = 0.f;

    for (int i = 0; i < C_TOTAL / 256; ++i) {
        const int c4i = i * 64 + lane;
        float4 w4 = w4p[c4i];
        #pragma unroll
        for (int b = 0; b < NB; ++b) {
            float4 g4 = ((const float4*)(g + (size_t)b * C_TOTAL))[c4i];
            acc[b] = fmaf(w4.x, g4.x, acc[b]);
            acc[b] = fmaf(w4.y, g4.y, acc[b]);
            acc[b] = fmaf(w4.z, g4.z, acc[b]);
            acc[b] = fmaf(w4.w, g4.w, acc[b]);
        }
    }
    #pragma unroll
    for (int b = 0; b < NB; ++b) {
        #pragma unroll
        for (int off = 32; off; off >>= 1) acc[b] += __shfl_down(acc[b], off, 64);
    }
    if (lane == 0) {
        #pragma unroll
        for (int b = 0; b < NB; ++b) out[(size_t)b * NK + k] = acc[b];
    }
}

extern "C" void kernel_launch(void* const* d_in, const int* in_sizes, int n_in,
                              void* d_out, int out_size, void* d_ws, size_t ws_size,
                              hipStream_t stream) {
    const float* l3  = (const float*)d_in[0];  // (16,1024,28,28)
    const float* l4  = (const float*)d_in[1];  // (16,2048,14,14)
    const float* Wl  = (const float*)d_in[2];  // (9,3072)
    const float* Wc  = (const float*)d_in[3];  // (2000,3072)
    const float* mod = (const float*)d_in[4];  // (1,3072,9)

    float* out  = (float*)d_out;
    float* cls  = out;             // 16*2000  = 32000
    float* maps = out + 32000;     // 16*9*784 = 112896
    float* af   = out + 144896;    // 16*3072*9 = 442368

    float* ab4p = (float*)d_ws;                       // 16*16*9*196 = 451584 floats
    float* g    = ab4p + 16 * NB * L_TOT * HW4;       // 16*3072 floats

    ab4_kernel <<<dim3(16, NB), 256, 0, stream>>>(l4, Wl, ab4p);
    maps_kernel<<<dim3(13, NB), 1024, 0, stream>>>(l3, Wl, ab4p, maps);
    pool_kernel<<<dim3(48, NB), 256, 0, stream>>>(l3, l4, maps, mod, af, g);
    class_kernel<<<NK / 4, 256, 0, stream>>>(Wc, g, cls);
}

// Round 3
// 241.692 us; speedup vs baseline: 2.2901x; 1.0191x over previous
//
#include <hip/hip_runtime.h>
#include <math.h>

// Problem constants
#define C_TOTAL 3072
#define C4 2048      // channels from l4 (upsampled half of concat: channels [0,2048))
#define C3 1024      // channels from l3 (channels [2048,3072))
#define HW  784      // 28*28
#define W_  28
#define HW4 196      // 14*14
#define W4  14
#define L_TOT 9      // landmarks + 1
#define NB  16       // batch
#define NK  2000     // classes
#define J3  16       // l3 channel chunks (64 ch each) for ab3 partials

// Bilinear upsample 14->28, align_corners=False (jax.image.resize semantics):
// src = 0.5*o - 0.25; even o=2j: taps (j-1, j) w (0.25, 0.75); odd o=2j+1: taps (j, j+1) w (0.75, 0.25); clamp.
__device__ __forceinline__ void up_taps(int o, int& i0, int& i1, float& w0, float& w1) {
    int j = o >> 1;
    if (o & 1) { i0 = j;                       i1 = (j + 1 < W4) ? j + 1 : W4 - 1; w0 = 0.75f; w1 = 0.25f; }
    else       { i0 = (j - 1 > 0) ? j - 1 : 0; i1 = j;                             w0 = 0.25f; w1 = 0.75f; }
}

// weight that source index s contributes to output index o (adjoint of the upsample)
__device__ __forceinline__ float wdown(int o, int s) {
    int i0, i1; float w0, w1;
    up_taps(o, i0, i1, w0, w1);
    return (i0 == s ? w0 : 0.f) + (i1 == s ? w1 : 0.f);
}

// ------------- K0: asq[l] = sum_c Wl[l][c]^2 -------------------------------------------------------
__global__ __launch_bounds__(256) void asq_kernel(const float* __restrict__ Wl,
                                                  float* __restrict__ asqp) {
    const int w = threadIdx.x >> 6, lane = threadIdx.x & 63;
    for (int l = w; l < L_TOT; l += 4) {
        float s = 0.f;
        const float* wrow = Wl + (size_t)l * C_TOTAL;
        for (int c = lane; c < C_TOTAL; c += 64) { float v = wrow[c]; s = fmaf(v, v, s); }
        #pragma unroll
        for (int off = 32; off; off >>= 1) s += __shfl_down(s, off, 64);
        if (lane == 0) asqp[l] = s;
    }
}

// ------------- K1a: ab4 partials — ab4[b,l,q] = sum_{c<2048} Wl[l,c]*l4[b,c,q] on the 14x14 grid ---
__global__ __launch_bounds__(256) void ab4_kernel(
    const float* __restrict__ l4, const float* __restrict__ Wl,
    float* __restrict__ ab4p)
{
    const int q  = threadIdx.x;
    const int cb = blockIdx.x;   // 0..15
    const int b  = blockIdx.y;
    if (q >= HW4) return;

    const float* l4b = l4 + (size_t)b * C4 * HW4;
    float acc[L_TOT];
    #pragma unroll
    for (int l = 0; l < L_TOT; ++l) acc[l] = 0.f;

    const int c0 = cb * 128;
    #pragma unroll 8
    for (int i = 0; i < 128; ++i) {
        const int c = c0 + i;                       // wave-uniform -> scalar weight loads
        float xv = l4b[(size_t)c * HW4 + q];        // coalesced over q
        const float* wc = Wl + c;
        #pragma unroll
        for (int l = 0; l < L_TOT; ++l) acc[l] = fmaf(wc[l * C_TOTAL], xv, acc[l]);
    }
    float* outp = ab4p + (size_t)(cb * NB + b) * (L_TOT * HW4) + q;
    #pragma unroll
    for (int l = 0; l < L_TOT; ++l) outp[l * HW4] = acc[l];
}

// ------------- K1b: ab3 partials — float4 pixel loads, 16 chunks of 64 channels ---------------------
// ab3p[(j*NB+b)][l][p] = sum_{c in chunk j} Wl[l,2048+c]*l3[b,c,p]
// Block 256 (196 active = float4 pixel groups). Grid (16 chunks, 16 b).
__global__ __launch_bounds__(256) void ab3_kernel(
    const float* __restrict__ l3, const float* __restrict__ Wl,
    float* __restrict__ ab3p)
{
    const int t = threadIdx.x;          // float4 pixel group 0..195
    const int j = blockIdx.x;           // channel chunk
    const int b = blockIdx.y;
    if (t >= HW / 4) return;

    const float4* l3b = (const float4*)(l3 + (size_t)b * C3 * HW);
    float4 acc[L_TOT];
    #pragma unroll
    for (int l = 0; l < L_TOT; ++l) acc[l] = make_float4(0.f, 0.f, 0.f, 0.f);

    const int c0 = j * (C3 / J3);
    #pragma unroll 8
    for (int i = 0; i < C3 / J3; ++i) {
        const int c = c0 + i;                               // wave-uniform
        float4 xv = l3b[(size_t)c * (HW / 4) + t];          // 1 KB per wave instr
        const float* wc = Wl + C4 + c;
        #pragma unroll
        for (int l = 0; l < L_TOT; ++l) {
            const float w = wc[l * C_TOTAL];                // scalar load
            acc[l].x = fmaf(w, xv.x, acc[l].x);
            acc[l].y = fmaf(w, xv.y, acc[l].y);
            acc[l].z = fmaf(w, xv.z, acc[l].z);
            acc[l].w = fmaf(w, xv.w, acc[l].w);
        }
    }
    float4* outp = (float4*)(ab3p + (size_t)(j * NB + b) * (L_TOT * HW));
    #pragma unroll
    for (int l = 0; l < L_TOT; ++l) outp[l * (HW / 4) + t] = acc[l];
}

// ------------- K1c: finalize — sum partials + upsample(ab4) + softmax -> maps -----------------------
// Thread = output pixel. Grid (4 pixel chunks of 256, 16 b). Softmax fully per-thread.
__global__ __launch_bounds__(256) void maps_fin_kernel(
    const float* __restrict__ ab3p, const float* __restrict__ ab4p,
    const float* __restrict__ asqp, float* __restrict__ maps_out)
{
    __shared__ float ab4s[L_TOT * HW4];
    __shared__ float asq_s[L_TOT];

    const int tid = threadIdx.x;
    const int b   = blockIdx.y;
    const int p   = blockIdx.x * 256 + tid;

    for (int v = tid; v < L_TOT * HW4; v += 256) {
        float s = 0.f;
        #pragma unroll
        for (int j = 0; j < 16; ++j) s += ab4p[(size_t)(j * NB + b) * (L_TOT * HW4) + v];
        ab4s[v] = s;
    }
    if (tid < L_TOT) asq_s[tid] = asqp[tid];
    __syncthreads();
    if (p >= HW) return;

    const int y = p / W_, x = p % W_;
    int y0, y1, x0, x1; float wy0, wy1, wx0, wx1;
    up_taps(y, y0, y1, wy0, wy1);
    up_taps(x, x0, x1, wx0, wx1);

    float lg[L_TOT];
    #pragma unroll
    for (int l = 0; l < L_TOT; ++l) {
        float s = 0.f;
        #pragma unroll
        for (int j = 0; j < J3; ++j)
            s += ab3p[((size_t)(j * NB + b) * L_TOT + l) * HW + p];   // coalesced over p
        const float* a = ab4s + l * HW4;
        float t0 = fmaf(a[y0 * W4 + x1], wx1, a[y0 * W4 + x0] * wx0);
        float t1 = fmaf(a[y1 * W4 + x1], wx1, a[y1 * W4 + x0] * wx0);
        float up = fmaf(t1, wy1, t0 * wy0);
        lg[l] = 2.f * (s + up) - asq_s[l];
    }
    float m = lg[0];
    #pragma unroll
    for (int l = 1; l < L_TOT; ++l) m = fmaxf(m, lg[l]);
    float sum = 0.f;
    #pragma unroll
    for (int l = 0; l < L_TOT; ++l) { lg[l] = __expf(lg[l] - m); sum += lg[l]; }
    const float inv = 1.f / sum;
    float* mp = maps_out + (size_t)b * L_TOT * HW + p;
    #pragma unroll
    for (int l = 0; l < L_TOT; ++l) mp[l * HW] = lg[l] * inv;
}

// ------------- K2: pooling -> all_features + g ------------------------------------------------------
// Block 256 = 4 waves x (4 ch-subgroups x 16 px-lanes); each lane owns 4 consecutive channels.
// l4 blocks (cblk<32): downsample-adjoint maps into LDS, read l4 directly (no upsample).
// l3 blocks: stage maps[9][784] into LDS. Block owns full pixel range -> no atomics.
__global__ __launch_bounds__(256) void pool_kernel(
    const float* __restrict__ l3, const float* __restrict__ l4,
    const float* __restrict__ maps, const float* __restrict__ modulation,
    float* __restrict__ af_out, float* __restrict__ g_out)
{
    __shared__ float msh[L_TOT * HW];   // 28224 B; l4 blocks use first 9*196

    const int tid  = threadIdx.x;
    const int b    = blockIdx.y;
    const int cblk = blockIdx.x;        // 0..47
    const bool isl4 = (cblk < 32);
    const float* mb = maps + (size_t)b * L_TOT * HW;

    if (isl4) {
        // maps_down[l][sy][sx] = sum_{oy,ox} wdown(oy,sy)*wdown(ox,sx)*maps[l][oy][ox]
        for (int v = tid; v < L_TOT * HW4; v += 256) {
            const int l = v / HW4, q = v % HW4;
            const int sy = q / W4, sx = q % W4;
            float s = 0.f;
            int oy0 = 2 * sy - 1; if (oy0 < 0) oy0 = 0;
            int oy1 = 2 * sy + 2; if (oy1 > 27) oy1 = 27;
            int ox0 = 2 * sx - 1; if (ox0 < 0) ox0 = 0;
            int ox1 = 2 * sx + 2; if (ox1 > 27) ox1 = 27;
            for (int oy = oy0; oy <= oy1; ++oy) {
                const float wy = wdown(oy, sy);
                const float* row = mb + l * HW + oy * W_;
                for (int ox = ox0; ox <= ox1; ++ox)
                    s = fmaf(wy * wdown(ox, sx), row[ox], s);
            }
            msh[v] = s;
        }
    } else {
        for (int v = tid; v < (L_TOT * HW) / 4; v += 256)
            ((float4*)msh)[v] = ((const float4*)mb)[v];
    }
    __syncthreads();

    const int   PMAX  = isl4 ? HW4 : HW;
    const float* xbase = isl4 ? (l4 + (size_t)b * C4 * HW4)
                              : (l3 + (size_t)b * C3 * HW);
    const int cloc0 = (isl4 ? cblk : (cblk - 32)) * 64;
    const int w = tid >> 6, s = (tid >> 4) & 3, t = tid & 15;
    const int cl = cloc0 + w * 16 + s * 4;      // local channel base of this lane's 4 channels

    float acc[4][L_TOT];
    #pragma unroll
    for (int j = 0; j < 4; ++j)
        #pragma unroll
        for (int l = 0; l < L_TOT; ++l) acc[j][l] = 0.f;

    const int kmax = isl4 ? 4 : 13;
    for (int k = 0; k < kmax; ++k) {
        const int p = (t << 2) + (k << 6);
        if (p < PMAX) {
            float4 m4[L_TOT];
            #pragma unroll
            for (int l = 0; l < L_TOT; ++l) m4[l] = *(const float4*)&msh[l * PMAX + p];
            #pragma unroll
            for (int j = 0; j < 4; ++j) {
                float4 x4 = *(const float4*)&xbase[(size_t)(cl + j) * PMAX + p];
                #pragma unroll
                for (int l = 0; l < L_TOT; ++l)
                    acc[j][l] = fmaf(x4.x, m4[l].x, fmaf(x4.y, m4[l].y,
                                fmaf(x4.z, m4[l].z, fmaf(x4.w, m4[l].w, acc[j][l]))));
            }
        }
    }

    // reduce across the 16 pixel-lanes of each subgroup
    #pragma unroll
    for (int j = 0; j < 4; ++j)
        #pragma unroll
        for (int l = 0; l < L_TOT; ++l) {
            float v = acc[j][l];
            v += __shfl_xor(v, 1, 16);
            v += __shfl_xor(v, 2, 16);
            v += __shfl_xor(v, 4, 16);
            v += __shfl_xor(v, 8, 16);
            acc[j][l] = v;
        }

    if (t == 0) {
        const float inv_hw = 1.f / 784.f;
        #pragma unroll
        for (int j = 0; j < 4; ++j) {
            const int cg = (isl4 ? 0 : C4) + cl + j;    // global concat channel
            float* afp = af_out + ((size_t)b * C_TOTAL + cg) * L_TOT;
            float gp = 0.f;
            #pragma unroll
            for (int l = 0; l < L_TOT; ++l) {
                float v = acc[j][l] * inv_hw;
                afp[l] = v;
                if (l < 8) gp = fmaf(modulation[cg * L_TOT + l], v, gp);
            }
            g_out[(size_t)b * C_TOTAL + cg] = gp * 0.125f;
        }
    }
}

// ------------- K3: class_scores = g (16x3072) @ W_class^T (3072x2000) -------------------------------
__global__ __launch_bounds__(256) void class_kernel(
    const float* __restrict__ Wc, const float* __restrict__ g,
    float* __restrict__ out)
{
    const int wv   = threadIdx.x >> 6;
    const int lane = threadIdx.x & 63;
    const int k    = blockIdx.x * 4 + wv;

    const float4* w4p = (const float4*)(Wc + (size_t)k * C_TOTAL);
    float acc[NB];
    #pragma unroll
    for (int b = 0; b < NB; ++b) acc[b] = 0.f;

    for (int i = 0; i < C_TOTAL / 256; ++i) {
        const int c4i = i * 64 + lane;
        float4 w4 = w4p[c4i];
        #pragma unroll
        for (int b = 0; b < NB; ++b) {
            float4 g4 = ((const float4*)(g + (size_t)b * C_TOTAL))[c4i];
            acc[b] = fmaf(w4.x, g4.x, acc[b]);
            acc[b] = fmaf(w4.y, g4.y, acc[b]);
            acc[b] = fmaf(w4.z, g4.z, acc[b]);
            acc[b] = fmaf(w4.w, g4.w, acc[b]);
        }
    }
    #pragma unroll
    for (int b = 0; b < NB; ++b) {
        #pragma unroll
        for (int off = 32; off; off >>= 1) acc[b] += __shfl_down(acc[b], off, 64);
    }
    if (lane == 0) {
        #pragma unroll
        for (int b = 0; b < NB; ++b) out[(size_t)b * NK + k] = acc[b];
    }
}

extern "C" void kernel_launch(void* const* d_in, const int* in_sizes, int n_in,
                              void* d_out, int out_size, void* d_ws, size_t ws_size,
                              hipStream_t stream) {
    const float* l3  = (const float*)d_in[0];  // (16,1024,28,28)
    const float* l4  = (const float*)d_in[1];  // (16,2048,14,14)
    const float* Wl  = (const float*)d_in[2];  // (9,3072)
    const float* Wc  = (const float*)d_in[3];  // (2000,3072)
    const float* mod = (const float*)d_in[4];  // (1,3072,9)

    float* out  = (float*)d_out;
    float* cls  = out;             // 16*2000  = 32000
    float* maps = out + 32000;     // 16*9*784 = 112896
    float* af   = out + 144896;    // 16*3072*9 = 442368

    float* ab4p = (float*)d_ws;                        // 16*16*9*196 = 451584 floats
    float* ab3p = ab4p + 16 * NB * L_TOT * HW4;        // 16*16*9*784 = 1806336 floats
    float* g    = ab3p + (size_t)J3 * NB * L_TOT * HW; // 16*3072 floats
    float* asqp = g + NB * C_TOTAL;                    // 9 floats

    asq_kernel <<<1, 256, 0, stream>>>(Wl, asqp);
    ab4_kernel <<<dim3(16, NB), 256, 0, stream>>>(l4, Wl, ab4p);
    ab3_kernel <<<dim3(J3, NB), 256, 0, stream>>>(l3, Wl, ab3p);
    maps_fin_kernel<<<dim3(4, NB), 256, 0, stream>>>(ab3p, ab4p, asqp, maps);
    pool_kernel<<<dim3(48, NB), 256, 0, stream>>>(l3, l4, maps, mod, af, g);
    class_kernel<<<NK / 4, 256, 0, stream>>>(Wc, g, cls);
}

// Round 4
// 201.992 us; speedup vs baseline: 2.7402x; 1.1965x over previous
//
#include <hip/hip_runtime.h>
#include <math.h>

// Problem constants
#define C_TOTAL 3072
#define C4 2048      // channels from l4 (upsampled half of concat: channels [0,2048))
#define C3 1024      // channels from l3 (channels [2048,3072))
#define HW  784      // 28*28
#define W_  28
#define HW4 196      // 14*14
#define W4  14
#define L_TOT 9      // landmarks + 1
#define NB  16       // batch
#define NK  2000     // classes
#define J3  16       // l3 channel chunks (64 ch each) for ab3 partials

// Bilinear upsample 14->28, align_corners=False (jax.image.resize semantics):
// src = 0.5*o - 0.25; even o=2j: taps (j-1, j) w (0.25, 0.75); odd o=2j+1: taps (j, j+1) w (0.75, 0.25); clamp.
__device__ __forceinline__ void up_taps(int o, int& i0, int& i1, float& w0, float& w1) {
    int j = o >> 1;
    if (o & 1) { i0 = j;                       i1 = (j + 1 < W4) ? j + 1 : W4 - 1; w0 = 0.75f; w1 = 0.25f; }
    else       { i0 = (j - 1 > 0) ? j - 1 : 0; i1 = j;                             w0 = 0.25f; w1 = 0.75f; }
}

// weight that source index s contributes to output index o (adjoint of the upsample)
__device__ __forceinline__ float wdown(int o, int s) {
    int i0, i1; float w0, w1;
    up_taps(o, i0, i1, w0, w1);
    return (i0 == s ? w0 : 0.f) + (i1 == s ? w1 : 0.f);
}

// ------------- K0: asq[l] = sum_c Wl[l][c]^2 — one block per l, 4 indep accumulators/thread --------
__global__ __launch_bounds__(256) void asq_kernel(const float* __restrict__ Wl,
                                                  float* __restrict__ asqp) {
    __shared__ float red[4];
    const int l   = blockIdx.x;          // 0..8
    const int tid = threadIdx.x;
    const float* wrow = Wl + (size_t)l * C_TOTAL;
    float s0 = 0.f, s1 = 0.f, s2 = 0.f, s3 = 0.f;
    // 3072/256 = 12 elems/thread; independent loads, no serial chain
    #pragma unroll
    for (int i = 0; i < 12; i += 4) {
        float a = wrow[tid + (i + 0) * 256];
        float b = wrow[tid + (i + 1) * 256];
        float c = wrow[tid + (i + 2) * 256];
        float d = wrow[tid + (i + 3) * 256];
        s0 = fmaf(a, a, s0); s1 = fmaf(b, b, s1);
        s2 = fmaf(c, c, s2); s3 = fmaf(d, d, s3);
    }
    float s = (s0 + s1) + (s2 + s3);
    #pragma unroll
    for (int off = 32; off; off >>= 1) s += __shfl_down(s, off, 64);
    const int w = tid >> 6, lane = tid & 63;
    if (lane == 0) red[w] = s;
    __syncthreads();
    if (tid == 0) asqp[l] = (red[0] + red[1]) + (red[2] + red[3]);
}

// ------------- K1a: ab4 partials — ab4[b,l,q] = sum_{c<2048} Wl[l,c]*l4[b,c,q] on the 14x14 grid ---
__global__ __launch_bounds__(256) void ab4_kernel(
    const float* __restrict__ l4, const float* __restrict__ Wl,
    float* __restrict__ ab4p)
{
    const int q  = threadIdx.x;
    const int cb = blockIdx.x;   // 0..15
    const int b  = blockIdx.y;
    if (q >= HW4) return;

    const float* l4b = l4 + (size_t)b * C4 * HW4;
    float acc[L_TOT];
    #pragma unroll
    for (int l = 0; l < L_TOT; ++l) acc[l] = 0.f;

    const int c0 = cb * 128;
    #pragma unroll 8
    for (int i = 0; i < 128; ++i) {
        const int c = c0 + i;                       // wave-uniform -> scalar weight loads
        float xv = l4b[(size_t)c * HW4 + q];        // coalesced over q
        const float* wc = Wl + c;
        #pragma unroll
        for (int l = 0; l < L_TOT; ++l) acc[l] = fmaf(wc[l * C_TOTAL], xv, acc[l]);
    }
    float* outp = ab4p + (size_t)(cb * NB + b) * (L_TOT * HW4) + q;
    #pragma unroll
    for (int l = 0; l < L_TOT; ++l) outp[l * HW4] = acc[l];
}

// ------------- K1b: ab3 partials — float4 pixel loads, 16 chunks of 64 channels ---------------------
// ab3p[(j*NB+b)][l][p] = sum_{c in chunk j} Wl[l,2048+c]*l3[b,c,p]
// Block 256 (196 active = float4 pixel groups). Grid (16 chunks, 16 b).
__global__ __launch_bounds__(256) void ab3_kernel(
    const float* __restrict__ l3, const float* __restrict__ Wl,
    float* __restrict__ ab3p)
{
    const int t = threadIdx.x;          // float4 pixel group 0..195
    const int j = blockIdx.x;           // channel chunk
    const int b = blockIdx.y;
    if (t >= HW / 4) return;

    const float4* l3b = (const float4*)(l3 + (size_t)b * C3 * HW);
    float4 acc[L_TOT];
    #pragma unroll
    for (int l = 0; l < L_TOT; ++l) acc[l] = make_float4(0.f, 0.f, 0.f, 0.f);

    const int c0 = j * (C3 / J3);
    #pragma unroll 8
    for (int i = 0; i < C3 / J3; ++i) {
        const int c = c0 + i;                               // wave-uniform
        float4 xv = l3b[(size_t)c * (HW / 4) + t];          // 1 KB per wave instr
        const float* wc = Wl + C4 + c;
        #pragma unroll
        for (int l = 0; l < L_TOT; ++l) {
            const float w = wc[l * C_TOTAL];                // scalar load
            acc[l].x = fmaf(w, xv.x, acc[l].x);
            acc[l].y = fmaf(w, xv.y, acc[l].y);
            acc[l].z = fmaf(w, xv.z, acc[l].z);
            acc[l].w = fmaf(w, xv.w, acc[l].w);
        }
    }
    float4* outp = (float4*)(ab3p + (size_t)(j * NB + b) * (L_TOT * HW));
    #pragma unroll
    for (int l = 0; l < L_TOT; ++l) outp[l * (HW / 4) + t] = acc[l];
}

// ------------- K1c: finalize — sum partials + upsample(ab4) + softmax -> maps -----------------------
// Thread = output pixel. Grid (4 pixel chunks of 256, 16 b). Softmax fully per-thread.
__global__ __launch_bounds__(256) void maps_fin_kernel(
    const float* __restrict__ ab3p, const float* __restrict__ ab4p,
    const float* __restrict__ asqp, float* __restrict__ maps_out)
{
    __shared__ float ab4s[L_TOT * HW4];
    __shared__ float asq_s[L_TOT];

    const int tid = threadIdx.x;
    const int b   = blockIdx.y;
    const int p   = blockIdx.x * 256 + tid;

    for (int v = tid; v < L_TOT * HW4; v += 256) {
        float s = 0.f;
        #pragma unroll
        for (int j = 0; j < 16; ++j) s += ab4p[(size_t)(j * NB + b) * (L_TOT * HW4) + v];
        ab4s[v] = s;
    }
    if (tid < L_TOT) asq_s[tid] = asqp[tid];
    __syncthreads();
    if (p >= HW) return;

    const int y = p / W_, x = p % W_;
    int y0, y1, x0, x1; float wy0, wy1, wx0, wx1;
    up_taps(y, y0, y1, wy0, wy1);
    up_taps(x, x0, x1, wx0, wx1);

    float lg[L_TOT];
    #pragma unroll
    for (int l = 0; l < L_TOT; ++l) {
        float s = 0.f;
        #pragma unroll
        for (int j = 0; j < J3; ++j)
            s += ab3p[((size_t)(j * NB + b) * L_TOT + l) * HW + p];   // coalesced over p
        const float* a = ab4s + l * HW4;
        float t0 = fmaf(a[y0 * W4 + x1], wx1, a[y0 * W4 + x0] * wx0);
        float t1 = fmaf(a[y1 * W4 + x1], wx1, a[y1 * W4 + x0] * wx0);
        float up = fmaf(t1, wy1, t0 * wy0);
        lg[l] = 2.f * (s + up) - asq_s[l];
    }
    float m = lg[0];
    #pragma unroll
    for (int l = 1; l < L_TOT; ++l) m = fmaxf(m, lg[l]);
    float sum = 0.f;
    #pragma unroll
    for (int l = 0; l < L_TOT; ++l) { lg[l] = __expf(lg[l] - m); sum += lg[l]; }
    const float inv = 1.f / sum;
    float* mp = maps_out + (size_t)b * L_TOT * HW + p;
    #pragma unroll
    for (int l = 0; l < L_TOT; ++l) mp[l * HW] = lg[l] * inv;
}

// ------------- K2: pooling -> all_features + g ------------------------------------------------------
// Block 256 = 4 waves x (4 ch-subgroups x 16 px-lanes); each lane owns 4 consecutive channels.
// l4 blocks (cblk<32): downsample-adjoint maps into LDS, read l4 directly (no upsample).
// l3 blocks: stage maps[9][784] into LDS. Block owns full pixel range -> no atomics.
__global__ __launch_bounds__(256) void pool_kernel(
    const float* __restrict__ l3, const float* __restrict__ l4,
    const float* __restrict__ maps, const float* __restrict__ modulation,
    float* __restrict__ af_out, float* __restrict__ g_out)
{
    __shared__ float msh[L_TOT * HW];   // 28224 B; l4 blocks use first 9*196

    const int tid  = threadIdx.x;
    const int b    = blockIdx.y;
    const int cblk = blockIdx.x;        // 0..47
    const bool isl4 = (cblk < 32);
    const float* mb = maps + (size_t)b * L_TOT * HW;

    if (isl4) {
        // maps_down[l][sy][sx] = sum_{oy,ox} wdown(oy,sy)*wdown(ox,sx)*maps[l][oy][ox]
        for (int v = tid; v < L_TOT * HW4; v += 256) {
            const int l = v / HW4, q = v % HW4;
            const int sy = q / W4, sx = q % W4;
            float s = 0.f;
            int oy0 = 2 * sy - 1; if (oy0 < 0) oy0 = 0;
            int oy1 = 2 * sy + 2; if (oy1 > 27) oy1 = 27;
            int ox0 = 2 * sx - 1; if (ox0 < 0) ox0 = 0;
            int ox1 = 2 * sx + 2; if (ox1 > 27) ox1 = 27;
            for (int oy = oy0; oy <= oy1; ++oy) {
                const float wy = wdown(oy, sy);
                const float* row = mb + l * HW + oy * W_;
                for (int ox = ox0; ox <= ox1; ++ox)
                    s = fmaf(wy * wdown(ox, sx), row[ox], s);
            }
            msh[v] = s;
        }
    } else {
        for (int v = tid; v < (L_TOT * HW) / 4; v += 256)
            ((float4*)msh)[v] = ((const float4*)mb)[v];
    }
    __syncthreads();

    const int   PMAX  = isl4 ? HW4 : HW;
    const float* xbase = isl4 ? (l4 + (size_t)b * C4 * HW4)
                              : (l3 + (size_t)b * C3 * HW);
    const int cloc0 = (isl4 ? cblk : (cblk - 32)) * 64;
    const int w = tid >> 6, s = (tid >> 4) & 3, t = tid & 15;
    const int cl = cloc0 + w * 16 + s * 4;      // local channel base of this lane's 4 channels

    float acc[4][L_TOT];
    #pragma unroll
    for (int j = 0; j < 4; ++j)
        #pragma unroll
        for (int l = 0; l < L_TOT; ++l) acc[j][l] = 0.f;

    const int kmax = isl4 ? 4 : 13;
    for (int k = 0; k < kmax; ++k) {
        const int p = (t << 2) + (k << 6);
        if (p < PMAX) {
            float4 m4[L_TOT];
            #pragma unroll
            for (int l = 0; l < L_TOT; ++l) m4[l] = *(const float4*)&msh[l * PMAX + p];
            #pragma unroll
            for (int j = 0; j < 4; ++j) {
                float4 x4 = *(const float4*)&xbase[(size_t)(cl + j) * PMAX + p];
                #pragma unroll
                for (int l = 0; l < L_TOT; ++l)
                    acc[j][l] = fmaf(x4.x, m4[l].x, fmaf(x4.y, m4[l].y,
                                fmaf(x4.z, m4[l].z, fmaf(x4.w, m4[l].w, acc[j][l]))));
            }
        }
    }

    // reduce across the 16 pixel-lanes of each subgroup
    #pragma unroll
    for (int j = 0; j < 4; ++j)
        #pragma unroll
        for (int l = 0; l < L_TOT; ++l) {
            float v = acc[j][l];
            v += __shfl_xor(v, 1, 16);
            v += __shfl_xor(v, 2, 16);
            v += __shfl_xor(v, 4, 16);
            v += __shfl_xor(v, 8, 16);
            acc[j][l] = v;
        }

    if (t == 0) {
        const float inv_hw = 1.f / 784.f;
        #pragma unroll
        for (int j = 0; j < 4; ++j) {
            const int cg = (isl4 ? 0 : C4) + cl + j;    // global concat channel
            float* afp = af_out + ((size_t)b * C_TOTAL + cg) * L_TOT;
            float gp = 0.f;
            #pragma unroll
            for (int l = 0; l < L_TOT; ++l) {
                float v = acc[j][l] * inv_hw;
                afp[l] = v;
                if (l < 8) gp = fmaf(modulation[cg * L_TOT + l], v, gp);
            }
            g_out[(size_t)b * C_TOTAL + cg] = gp * 0.125f;
        }
    }
}

// ------------- K3: class_scores = g (16x3072) @ W_class^T (3072x2000) -------------------------------
__global__ __launch_bounds__(256) void class_kernel(
    const float* __restrict__ Wc, const float* __restrict__ g,
    float* __restrict__ out)
{
    const int wv   = threadIdx.x >> 6;
    const int lane = threadIdx.x & 63;
    const int k    = blockIdx.x * 4 + wv;

    const float4* w4p = (const float4*)(Wc + (size_t)k * C_TOTAL);
    float acc[NB];
    #pragma unroll
    for (int b = 0; b < NB; ++b) acc[b] = 0.f;

    for (int i = 0; i < C_TOTAL / 256; ++i) {
        const int c4i = i * 64 + lane;
        float4 w4 = w4p[c4i];
        #pragma unroll
        for (int b = 0; b < NB; ++b) {
            float4 g4 = ((const float4*)(g + (size_t)b * C_TOTAL))[c4i];
            acc[b] = fmaf(w4.x, g4.x, acc[b]);
            acc[b] = fmaf(w4.y, g4.y, acc[b]);
            acc[b] = fmaf(w4.z, g4.z, acc[b]);
            acc[b] = fmaf(w4.w, g4.w, acc[b]);
        }
    }
    #pragma unroll
    for (int b = 0; b < NB; ++b) {
        #pragma unroll
        for (int off = 32; off; off >>= 1) acc[b] += __shfl_down(acc[b], off, 64);
    }
    if (lane == 0) {
        #pragma unroll
        for (int b = 0; b < NB; ++b) out[(size_t)b * NK + k] = acc[b];
    }
}

extern "C" void kernel_launch(void* const* d_in, const int* in_sizes, int n_in,
                              void* d_out, int out_size, void* d_ws, size_t ws_size,
                              hipStream_t stream) {
    const float* l3  = (const float*)d_in[0];  // (16,1024,28,28)
    const float* l4  = (const float*)d_in[1];  // (16,2048,14,14)
    const float* Wl  = (const float*)d_in[2];  // (9,3072)
    const float* Wc  = (const float*)d_in[3];  // (2000,3072)
    const float* mod = (const float*)d_in[4];  // (1,3072,9)

    float* out  = (float*)d_out;
    float* cls  = out;             // 16*2000  = 32000
    float* maps = out + 32000;     // 16*9*784 = 112896
    float* af   = out + 144896;    // 16*3072*9 = 442368

    float* ab4p = (float*)d_ws;                        // 16*16*9*196 = 451584 floats
    float* ab3p = ab4p + 16 * NB * L_TOT * HW4;        // 16*16*9*784 = 1806336 floats
    float* g    = ab3p + (size_t)J3 * NB * L_TOT * HW; // 16*3072 floats
    float* asqp = g + NB * C_TOTAL;                    // 9 floats

    asq_kernel <<<L_TOT, 256, 0, stream>>>(Wl, asqp);
    ab4_kernel <<<dim3(16, NB), 256, 0, stream>>>(l4, Wl, ab4p);
    ab3_kernel <<<dim3(J3, NB), 256, 0, stream>>>(l3, Wl, ab3p);
    maps_fin_kernel<<<dim3(4, NB), 256, 0, stream>>>(ab3p, ab4p, asqp, maps);
    pool_kernel<<<dim3(48, NB), 256, 0, stream>>>(l3, l4, maps, mod, af, g);
    class_kernel<<<NK / 4, 256, 0, stream>>>(Wc, g, cls);
}

// Round 5
// 189.519 us; speedup vs baseline: 2.9206x; 1.0658x over previous
//
#include <hip/hip_runtime.h>
#include <math.h>

// Problem constants
#define C_TOTAL 3072
#define C4 2048      // channels from l4 (upsampled half of concat: channels [0,2048))
#define C3 1024      // channels from l3 (channels [2048,3072))
#define HW  784      // 28*28
#define W_  28
#define HW4 196      // 14*14
#define W4  14
#define L_TOT 9      // landmarks + 1
#define NB  16       // batch
#define NK  2000     // classes
#define J3  16       // l3 channel chunks (64 ch each) for ab3 partials

// Bilinear upsample 14->28, align_corners=False (jax.image.resize semantics):
// src = 0.5*o - 0.25; even o=2j: taps (j-1, j) w (0.25, 0.75); odd o=2j+1: taps (j, j+1) w (0.75, 0.25); clamp.
__device__ __forceinline__ void up_taps(int o, int& i0, int& i1, float& w0, float& w1) {
    int j = o >> 1;
    if (o & 1) { i0 = j;                       i1 = (j + 1 < W4) ? j + 1 : W4 - 1; w0 = 0.75f; w1 = 0.25f; }
    else       { i0 = (j - 1 > 0) ? j - 1 : 0; i1 = j;                             w0 = 0.25f; w1 = 0.75f; }
}

// weight that source index s contributes to output index o (adjoint of the upsample)
__device__ __forceinline__ float wdown(int o, int s) {
    int i0, i1; float w0, w1;
    up_taps(o, i0, i1, w0, w1);
    return (i0 == s ? w0 : 0.f) + (i1 == s ? w1 : 0.f);
}

// ------------- K1: fused front section — block-specialized on blockIdx.x ----------------------------
// x in [0,16):   ab4 partials  ab4p[(x*NB+b)][l][q] = sum_{c in 128-chunk x} Wl[l,c]*l4[b,c,q]
// x in [16,32):  ab3 partials  ab3p[((x-16)*NB+b)][l][p] (float4 pixel loads, 64-ch chunks)
// x == 32, b==0: asq[l] = sum_c Wl[l][c]^2
// Grid (33, 16) = 528 blocks ≈ 2/CU -> front-section latency hiding.
__global__ __launch_bounds__(256) void abx_kernel(
    const float* __restrict__ l3, const float* __restrict__ l4,
    const float* __restrict__ Wl,
    float* __restrict__ ab4p, float* __restrict__ ab3p, float* __restrict__ asqp)
{
    const int bx = blockIdx.x;
    const int b  = blockIdx.y;
    const int tid = threadIdx.x;

    if (bx < 16) {
        // ---- ab4 section ----
        const int q = tid;
        if (q >= HW4) return;
        const float* l4b = l4 + (size_t)b * C4 * HW4;
        float acc[L_TOT];
        #pragma unroll
        for (int l = 0; l < L_TOT; ++l) acc[l] = 0.f;
        const int c0 = bx * 128;
        #pragma unroll 8
        for (int i = 0; i < 128; ++i) {
            const int c = c0 + i;                       // wave-uniform -> scalar weight loads
            float xv = l4b[(size_t)c * HW4 + q];        // coalesced over q
            const float* wc = Wl + c;
            #pragma unroll
            for (int l = 0; l < L_TOT; ++l) acc[l] = fmaf(wc[l * C_TOTAL], xv, acc[l]);
        }
        float* outp = ab4p + (size_t)(bx * NB + b) * (L_TOT * HW4) + q;
        #pragma unroll
        for (int l = 0; l < L_TOT; ++l) outp[l * HW4] = acc[l];
    } else if (bx < 32) {
        // ---- ab3 section ----
        const int t = tid;                  // float4 pixel group 0..195
        const int j = bx - 16;              // channel chunk
        if (t >= HW / 4) return;
        const float4* l3b = (const float4*)(l3 + (size_t)b * C3 * HW);
        float4 acc[L_TOT];
        #pragma unroll
        for (int l = 0; l < L_TOT; ++l) acc[l] = make_float4(0.f, 0.f, 0.f, 0.f);
        const int c0 = j * (C3 / J3);
        #pragma unroll 8
        for (int i = 0; i < C3 / J3; ++i) {
            const int c = c0 + i;                               // wave-uniform
            float4 xv = l3b[(size_t)c * (HW / 4) + t];          // 1 KB per wave instr
            const float* wc = Wl + C4 + c;
            #pragma unroll
            for (int l = 0; l < L_TOT; ++l) {
                const float w = wc[l * C_TOTAL];                // scalar load
                acc[l].x = fmaf(w, xv.x, acc[l].x);
                acc[l].y = fmaf(w, xv.y, acc[l].y);
                acc[l].z = fmaf(w, xv.z, acc[l].z);
                acc[l].w = fmaf(w, xv.w, acc[l].w);
            }
        }
        float4* outp = (float4*)(ab3p + (size_t)(j * NB + b) * (L_TOT * HW));
        #pragma unroll
        for (int l = 0; l < L_TOT; ++l) outp[l * (HW / 4) + t] = acc[l];
    } else {
        // ---- asq section (one block total) ----
        if (b != 0) return;
        __shared__ float red[4];
        for (int l = 0; l < L_TOT; ++l) {
            const float* wrow = Wl + (size_t)l * C_TOTAL;
            float s0 = 0.f, s1 = 0.f, s2 = 0.f, s3 = 0.f;
            {
                float a = wrow[tid +  0 * 256];
                float bb = wrow[tid + 1 * 256];
                float c = wrow[tid +  2 * 256];
                float d = wrow[tid +  3 * 256];
                float e = wrow[tid +  4 * 256];
                float f = wrow[tid +  5 * 256];
                float gg = wrow[tid + 6 * 256];
                float h = wrow[tid +  7 * 256];
                float i2 = wrow[tid + 8 * 256];
                float j2 = wrow[tid + 9 * 256];
                float k2 = wrow[tid + 10 * 256];
                float m2 = wrow[tid + 11 * 256];
                s0 = fmaf(a, a, fmaf(e, e, i2 * i2));
                s1 = fmaf(bb, bb, fmaf(f, f, j2 * j2));
                s2 = fmaf(c, c, fmaf(gg, gg, k2 * k2));
                s3 = fmaf(d, d, fmaf(h, h, m2 * m2));
            }
            float s = (s0 + s1) + (s2 + s3);
            #pragma unroll
            for (int off = 32; off; off >>= 1) s += __shfl_down(s, off, 64);
            const int w = tid >> 6, lane = tid & 63;
            if (lane == 0) red[w] = s;
            __syncthreads();
            if (tid == 0) asqp[l] = (red[0] + red[1]) + (red[2] + red[3]);
            __syncthreads();
        }
    }
}

// ------------- K2: finalize — sum partials + upsample(ab4) + softmax -> maps -----------------------
// Thread = output pixel. Grid (4 pixel chunks of 256, 16 b). Softmax fully per-thread.
__global__ __launch_bounds__(256) void maps_fin_kernel(
    const float* __restrict__ ab3p, const float* __restrict__ ab4p,
    const float* __restrict__ asqp, float* __restrict__ maps_out)
{
    __shared__ float ab4s[L_TOT * HW4];
    __shared__ float asq_s[L_TOT];

    const int tid = threadIdx.x;
    const int b   = blockIdx.y;
    const int p   = blockIdx.x * 256 + tid;

    for (int v = tid; v < L_TOT * HW4; v += 256) {
        float s = 0.f;
        #pragma unroll
        for (int j = 0; j < 16; ++j) s += ab4p[(size_t)(j * NB + b) * (L_TOT * HW4) + v];
        ab4s[v] = s;
    }
    if (tid < L_TOT) asq_s[tid] = asqp[tid];
    __syncthreads();
    if (p >= HW) return;

    const int y = p / W_, x = p % W_;
    int y0, y1, x0, x1; float wy0, wy1, wx0, wx1;
    up_taps(y, y0, y1, wy0, wy1);
    up_taps(x, x0, x1, wx0, wx1);

    float lg[L_TOT];
    #pragma unroll
    for (int l = 0; l < L_TOT; ++l) {
        float s = 0.f;
        #pragma unroll
        for (int j = 0; j < J3; ++j)
            s += ab3p[((size_t)(j * NB + b) * L_TOT + l) * HW + p];   // coalesced over p
        const float* a = ab4s + l * HW4;
        float t0 = fmaf(a[y0 * W4 + x1], wx1, a[y0 * W4 + x0] * wx0);
        float t1 = fmaf(a[y1 * W4 + x1], wx1, a[y1 * W4 + x0] * wx0);
        float up = fmaf(t1, wy1, t0 * wy0);
        lg[l] = 2.f * (s + up) - asq_s[l];
    }
    float m = lg[0];
    #pragma unroll
    for (int l = 1; l < L_TOT; ++l) m = fmaxf(m, lg[l]);
    float sum = 0.f;
    #pragma unroll
    for (int l = 0; l < L_TOT; ++l) { lg[l] = __expf(lg[l] - m); sum += lg[l]; }
    const float inv = 1.f / sum;
    float* mp = maps_out + (size_t)b * L_TOT * HW + p;
    #pragma unroll
    for (int l = 0; l < L_TOT; ++l) mp[l * HW] = lg[l] * inv;
}

// ------------- K3: pooling -> all_features + g ------------------------------------------------------
// Block 256 = 4 waves x (4 ch-subgroups x 16 px-lanes); each lane owns 4 consecutive channels.
// l4 blocks (cblk<32): downsample-adjoint maps into LDS, read l4 directly (no upsample).
// l3 blocks: stage maps[9][784] into LDS. Block owns full pixel range -> no atomics.
__global__ __launch_bounds__(256) void pool_kernel(
    const float* __restrict__ l3, const float* __restrict__ l4,
    const float* __restrict__ maps, const float* __restrict__ modulation,
    float* __restrict__ af_out, float* __restrict__ g_out)
{
    __shared__ float msh[L_TOT * HW];   // 28224 B; l4 blocks use first 9*196

    const int tid  = threadIdx.x;
    const int b    = blockIdx.y;
    const int cblk = blockIdx.x;        // 0..47
    const bool isl4 = (cblk < 32);
    const float* mb = maps + (size_t)b * L_TOT * HW;

    if (isl4) {
        // maps_down[l][sy][sx] = sum_{oy,ox} wdown(oy,sy)*wdown(ox,sx)*maps[l][oy][ox]
        for (int v = tid; v < L_TOT * HW4; v += 256) {
            const int l = v / HW4, q = v % HW4;
            const int sy = q / W4, sx = q % W4;
            float s = 0.f;
            int oy0 = 2 * sy - 1; if (oy0 < 0) oy0 = 0;
            int oy1 = 2 * sy + 2; if (oy1 > 27) oy1 = 27;
            int ox0 = 2 * sx - 1; if (ox0 < 0) ox0 = 0;
            int ox1 = 2 * sx + 2; if (ox1 > 27) ox1 = 27;
            for (int oy = oy0; oy <= oy1; ++oy) {
                const float wy = wdown(oy, sy);
                const float* row = mb + l * HW + oy * W_;
                for (int ox = ox0; ox <= ox1; ++ox)
                    s = fmaf(wy * wdown(ox, sx), row[ox], s);
            }
            msh[v] = s;
        }
    } else {
        for (int v = tid; v < (L_TOT * HW) / 4; v += 256)
            ((float4*)msh)[v] = ((const float4*)mb)[v];
    }
    __syncthreads();

    const int   PMAX  = isl4 ? HW4 : HW;
    const float* xbase = isl4 ? (l4 + (size_t)b * C4 * HW4)
                              : (l3 + (size_t)b * C3 * HW);
    const int cloc0 = (isl4 ? cblk : (cblk - 32)) * 64;
    const int w = tid >> 6, s = (tid >> 4) & 3, t = tid & 15;
    const int cl = cloc0 + w * 16 + s * 4;      // local channel base of this lane's 4 channels

    float acc[4][L_TOT];
    #pragma unroll
    for (int j = 0; j < 4; ++j)
        #pragma unroll
        for (int l = 0; l < L_TOT; ++l) acc[j][l] = 0.f;

    const int kmax = isl4 ? 4 : 13;
    for (int k = 0; k < kmax; ++k) {
        const int p = (t << 2) + (k << 6);
        if (p < PMAX) {
            float4 m4[L_TOT];
            #pragma unroll
            for (int l = 0; l < L_TOT; ++l) m4[l] = *(const float4*)&msh[l * PMAX + p];
            #pragma unroll
            for (int j = 0; j < 4; ++j) {
                float4 x4 = *(const float4*)&xbase[(size_t)(cl + j) * PMAX + p];
                #pragma unroll
                for (int l = 0; l < L_TOT; ++l)
                    acc[j][l] = fmaf(x4.x, m4[l].x, fmaf(x4.y, m4[l].y,
                                fmaf(x4.z, m4[l].z, fmaf(x4.w, m4[l].w, acc[j][l]))));
            }
        }
    }

    // reduce across the 16 pixel-lanes of each subgroup
    #pragma unroll
    for (int j = 0; j < 4; ++j)
        #pragma unroll
        for (int l = 0; l < L_TOT; ++l) {
            float v = acc[j][l];
            v += __shfl_xor(v, 1, 16);
            v += __shfl_xor(v, 2, 16);
            v += __shfl_xor(v, 4, 16);
            v += __shfl_xor(v, 8, 16);
            acc[j][l] = v;
        }

    if (t == 0) {
        const float inv_hw = 1.f / 784.f;
        #pragma unroll
        for (int j = 0; j < 4; ++j) {
            const int cg = (isl4 ? 0 : C4) + cl + j;    // global concat channel
            float* afp = af_out + ((size_t)b * C_TOTAL + cg) * L_TOT;
            float gp = 0.f;
            #pragma unroll
            for (int l = 0; l < L_TOT; ++l) {
                float v = acc[j][l] * inv_hw;
                afp[l] = v;
                if (l < 8) gp = fmaf(modulation[cg * L_TOT + l], v, gp);
            }
            g_out[(size_t)b * C_TOTAL + cg] = gp * 0.125f;
        }
    }
}

// ------------- K4: class_scores = g (16x3072) @ W_class^T (3072x2000) -------------------------------
__global__ __launch_bounds__(256) void class_kernel(
    const float* __restrict__ Wc, const float* __restrict__ g,
    float* __restrict__ out)
{
    const int wv   = threadIdx.x >> 6;
    const int lane = threadIdx.x & 63;
    const int k    = blockIdx.x * 4 + wv;

    const float4* w4p = (const float4*)(Wc + (size_t)k * C_TOTAL);
    float acc[NB];
    #pragma unroll
    for (int b = 0; b < NB; ++b) acc[b] = 0.f;

    for (int i = 0; i < C_TOTAL / 256; ++i) {
        const int c4i = i * 64 + lane;
        float4 w4 = w4p[c4i];
        #pragma unroll
        for (int b = 0; b < NB; ++b) {
            float4 g4 = ((const float4*)(g + (size_t)b * C_TOTAL))[c4i];
            acc[b] = fmaf(w4.x, g4.x, acc[b]);
            acc[b] = fmaf(w4.y, g4.y, acc[b]);
            acc[b] = fmaf(w4.z, g4.z, acc[b]);
            acc[b] = fmaf(w4.w, g4.w, acc[b]);
        }
    }
    #pragma unroll
    for (int b = 0; b < NB; ++b) {
        #pragma unroll
        for (int off = 32; off; off >>= 1) acc[b] += __shfl_down(acc[b], off, 64);
    }
    if (lane == 0) {
        #pragma unroll
        for (int b = 0; b < NB; ++b) out[(size_t)b * NK + k] = acc[b];
    }
}

extern "C" void kernel_launch(void* const* d_in, const int* in_sizes, int n_in,
                              void* d_out, int out_size, void* d_ws, size_t ws_size,
                              hipStream_t stream) {
    const float* l3  = (const float*)d_in[0];  // (16,1024,28,28)
    const float* l4  = (const float*)d_in[1];  // (16,2048,14,14)
    const float* Wl  = (const float*)d_in[2];  // (9,3072)
    const float* Wc  = (const float*)d_in[3];  // (2000,3072)
    const float* mod = (const float*)d_in[4];  // (1,3072,9)

    float* out  = (float*)d_out;
    float* cls  = out;             // 16*2000  = 32000
    float* maps = out + 32000;     // 16*9*784 = 112896
    float* af   = out + 144896;    // 16*3072*9 = 442368

    float* ab4p = (float*)d_ws;                        // 16*16*9*196 = 451584 floats
    float* ab3p = ab4p + 16 * NB * L_TOT * HW4;        // 16*16*9*784 = 1806336 floats
    float* g    = ab3p + (size_t)J3 * NB * L_TOT * HW; // 16*3072 floats
    float* asqp = g + NB * C_TOTAL;                    // 9 floats

    abx_kernel     <<<dim3(33, NB), 256, 0, stream>>>(l3, l4, Wl, ab4p, ab3p, asqp);
    maps_fin_kernel<<<dim3(4, NB), 256, 0, stream>>>(ab3p, ab4p, asqp, maps);
    pool_kernel    <<<dim3(48, NB), 256, 0, stream>>>(l3, l4, maps, mod, af, g);
    class_kernel   <<<NK / 4, 256, 0, stream>>>(Wc, g, cls);
}